// Round 1
// baseline (850.455 us; speedup 1.0000x reference)
//
#include <hip/hip_runtime.h>

// Discriminator2: logits = [sc1 (N) | sc2 (4xN) | sc2 again (4xN)]
//   v[n]    = W @ h_c[n]                (the 52.4 GFLOP part -> bf16 MFMA)
//   sc1[n]  = h_pl[n] . v[n] + b
//   sc2[s,n]= h_c[sample[s,n]] . v[n] + b
//
// One fused kernel: block = 64 nodes, 512 threads (8 waves).
// Wave w computes v columns [64w, 64w+64) via mfma_f32_16x16x32_bf16.
// A-tile (h_c rows, bf16, XOR-swizzled) lives in LDS; after the GEMM the
// same LDS is reused for the f32 v-tile (union, 128KB) for the dot epilogue.

#define NN 100000
#define DD 512
#define SS 4
#define BM 64

typedef __attribute__((ext_vector_type(8))) short bf16x8;
typedef __attribute__((ext_vector_type(4))) float f32x4;

__device__ __forceinline__ short f2bf(float f) {
  // round-to-nearest-even f32 -> bf16
  unsigned u = __builtin_bit_cast(unsigned, f);
  u += 0x7fffu + ((u >> 16) & 1u);
  return (short)(u >> 16);
}

__global__ __launch_bounds__(512, 2)
void disc2(const float* __restrict__ hc, const float* __restrict__ hpl,
           const int* __restrict__ smp, const float* __restrict__ W,
           const float* __restrict__ bias, float* __restrict__ out) {
  // union: [0,64KB) = A-tile bf16 [64][512] (swizzled); after barrier,
  // [0,128KB) = v f32 [64][512] (swizzled). +1KB sample indices.
  __shared__ __align__(16) char smem[BM * DD * 4 + SS * BM * 4];
  int* samp = (int*)(smem + BM * DD * 4);

  const int t = threadIdx.x;
  const int w = t >> 6;        // wave 0..7
  const int l = t & 63;
  const int lmod = l & 15;
  const int ldiv = l >> 4;
  const int n0 = blockIdx.x * BM;

  // ---- stage sample indices (int32 per harness convention) ----
  if (t < SS * BM) {
    int s = t >> 6, r = t & 63;
    int n = n0 + r;
    samp[t] = (n < NN) ? smp[s * NN + n] : 0;
  }

  // ---- stage A tile: h_c rows -> bf16 LDS, swizzle byte^=((row&7)<<4) ----
  {
    int row = t >> 3;                 // 8 threads per row
    int c0 = (t & 7) * 64;            // 64 contiguous cols per thread
    int n = n0 + row;
    unsigned rb = (unsigned)row * 1024u;
    unsigned sw = ((unsigned)row & 7u) << 4;
#pragma unroll
    for (int i = 0; i < 8; ++i) {
      int c = c0 + i * 8;
      bf16x8 h;
      if (n < NN) {
        f32x4 x0 = *(const f32x4*)(hc + (size_t)n * DD + c);
        f32x4 x1 = *(const f32x4*)(hc + (size_t)n * DD + c + 4);
        h[0] = f2bf(x0.x); h[1] = f2bf(x0.y); h[2] = f2bf(x0.z); h[3] = f2bf(x0.w);
        h[4] = f2bf(x1.x); h[5] = f2bf(x1.y); h[6] = f2bf(x1.z); h[7] = f2bf(x1.w);
      } else {
        h = (bf16x8)0;                // zero rows beyond N -> v rows = 0
      }
      unsigned addr = rb + (((unsigned)(c * 2)) ^ sw);
      *(bf16x8*)(smem + addr) = h;
    }
  }
  __syncthreads();

  // ---- GEMM: v[0:64][w*64 : w*64+64] via 16x16x32 bf16 MFMA ----
  f32x4 acc[4][4];
#pragma unroll
  for (int i = 0; i < 4; ++i)
#pragma unroll
    for (int j = 0; j < 4; ++j) acc[i][j] = (f32x4)0.0f;

  const float* Wbase = W + (size_t)(w * 64) * DD;

  for (int kt = 0; kt < DD / 32; ++kt) {
    int ke = kt * 32 + 8 * ldiv;      // this lane's k start (8 elems)
    bf16x8 a[4];
#pragma unroll
    for (int mf = 0; mf < 4; ++mf) {
      int row = mf * 16 + lmod;
      unsigned addr = (unsigned)row * 1024u +
                      (((unsigned)(ke * 2)) ^ (((unsigned)row & 7u) << 4));
      a[mf] = *(const bf16x8*)(smem + addr);
    }
#pragma unroll
    for (int nf = 0; nf < 4; ++nf) {
      const float* wp = Wbase + (size_t)(nf * 16 + lmod) * DD + ke;
      f32x4 w0 = *(const f32x4*)(wp);
      f32x4 w1 = *(const f32x4*)(wp + 4);
      bf16x8 b;
      b[0] = f2bf(w0.x); b[1] = f2bf(w0.y); b[2] = f2bf(w0.z); b[3] = f2bf(w0.w);
      b[4] = f2bf(w1.x); b[5] = f2bf(w1.y); b[6] = f2bf(w1.z); b[7] = f2bf(w1.w);
#pragma unroll
      for (int mf = 0; mf < 4; ++mf)
        acc[mf][nf] = __builtin_amdgcn_mfma_f32_16x16x32_bf16(a[mf], b, acc[mf][nf], 0, 0, 0);
    }
  }

  __syncthreads();   // all waves done reading A-tile before v overwrites it

  // ---- scatter acc -> v_lds (f32, swizzled). C/D map: col=lane&15, row=(lane>>4)*4+j ----
  {
    const int colbase = w * 64;
#pragma unroll
    for (int mf = 0; mf < 4; ++mf)
#pragma unroll
      for (int j = 0; j < 4; ++j) {
        int row = mf * 16 + ldiv * 4 + j;
        unsigned rb = (unsigned)row * 2048u;
        unsigned sw = ((unsigned)row & 7u) << 4;
#pragma unroll
        for (int nf = 0; nf < 4; ++nf) {
          int col = colbase + nf * 16 + lmod;
          unsigned addr = rb + (((unsigned)(col * 4)) ^ sw);
          *(float*)(smem + addr) = acc[mf][nf][j];
        }
      }
  }
  __syncthreads();

  // ---- epilogue: per row, 8 lanes dot v against h_pl + 4 gathered h_c rows ----
  {
    int row = w * 8 + (l >> 3);       // 0..63
    int q = l & 7;                    // 8 lanes per row, 64 cols each
    int n = n0 + row;
    if (n < NN) {
      int m0 = samp[0 * BM + row];
      int m1 = samp[1 * BM + row];
      int m2 = samp[2 * BM + row];
      int m3 = samp[3 * BM + row];
      const float* xp = hpl + (size_t)n * DD + q * 64;
      const float* g0 = hc + (size_t)m0 * DD + q * 64;
      const float* g1 = hc + (size_t)m1 * DD + q * 64;
      const float* g2 = hc + (size_t)m2 * DD + q * 64;
      const float* g3 = hc + (size_t)m3 * DD + q * 64;
      float p0 = 0.f, p1 = 0.f, p2 = 0.f, p3 = 0.f, p4 = 0.f;
      unsigned rb = (unsigned)row * 2048u;
      unsigned sw = ((unsigned)row & 7u) << 4;
#pragma unroll 4
      for (int i = 0; i < 16; ++i) {
        unsigned addr = rb + (((unsigned)((q * 64 + i * 4) * 4)) ^ sw);
        f32x4 v4 = *(const f32x4*)(smem + addr);
        f32x4 a0 = *(const f32x4*)(xp + i * 4);
        f32x4 b0 = *(const f32x4*)(g0 + i * 4);
        f32x4 b1 = *(const f32x4*)(g1 + i * 4);
        f32x4 b2 = *(const f32x4*)(g2 + i * 4);
        f32x4 b3 = *(const f32x4*)(g3 + i * 4);
        p0 += v4.x * a0.x + v4.y * a0.y + v4.z * a0.z + v4.w * a0.w;
        p1 += v4.x * b0.x + v4.y * b0.y + v4.z * b0.z + v4.w * b0.w;
        p2 += v4.x * b1.x + v4.y * b1.y + v4.z * b1.z + v4.w * b1.w;
        p3 += v4.x * b2.x + v4.y * b2.y + v4.z * b2.z + v4.w * b2.w;
        p4 += v4.x * b3.x + v4.y * b3.y + v4.z * b3.z + v4.w * b3.w;
      }
      // reduce over the 8 lanes (bits 0..2) sharing this row
#pragma unroll
      for (int off = 1; off < 8; off <<= 1) {
        p0 += __shfl_xor(p0, off);
        p1 += __shfl_xor(p1, off);
        p2 += __shfl_xor(p2, off);
        p3 += __shfl_xor(p3, off);
        p4 += __shfl_xor(p4, off);
      }
      if (q == 0) {
        float bb = bias[0];
        out[n] = p0 + bb;
        float v1 = p1 + bb; out[NN + 0 * NN + n] = v1; out[NN + 4 * NN + n] = v1;
        float v2 = p2 + bb; out[NN + 1 * NN + n] = v2; out[NN + 5 * NN + n] = v2;
        float v3 = p3 + bb; out[NN + 2 * NN + n] = v3; out[NN + 6 * NN + n] = v3;
        float v4s = p4 + bb; out[NN + 3 * NN + n] = v4s; out[NN + 7 * NN + n] = v4s;
      }
    }
  }
}

extern "C" void kernel_launch(void* const* d_in, const int* in_sizes, int n_in,
                              void* d_out, int out_size, void* d_ws, size_t ws_size,
                              hipStream_t stream) {
  const float* hc  = (const float*)d_in[0];   // h_c  [1,N,D]
  const float* hpl = (const float*)d_in[1];   // h_pl [1,N,D]
  const int*   smp = (const int*)d_in[2];     // sample_list [S,N]
  const float* W   = (const float*)d_in[3];   // W [1,D,D]
  const float* b   = (const float*)d_in[4];   // b [1]
  float* out = (float*)d_out;                 // [N + 2*S*N]
  (void)in_sizes; (void)n_in; (void)out_size; (void)d_ws; (void)ws_size;

  dim3 grid((NN + BM - 1) / BM);   // 1563
  dim3 block(512);
  disc2<<<grid, block, 0, stream>>>(hc, hpl, smp, W, b, out);
}

// Round 2
// 591.682 us; speedup vs baseline: 1.4374x; 1.4374x over previous
//
#include <hip/hip_runtime.h>

// Discriminator2: logits = [sc1 (N) | sc2 (4xN) | sc2 (4xN) again]
//   v[n][d]  = sum_e W[d][e] h_c[n][e]        (52.4 GFLOP -> bf16 MFMA)
//   sc1[n]   = h_pl[n] . v[n] + b
//   sc2[s,n] = h_c[sample[s,n]] . v[n] + b
//
// Block = 64 nodes, 512 threads (8 waves), wave w owns v-columns [64w,64w+64).
// A-tile (h_c rows, bf16, XOR-swizzled) in LDS; epilogue dots run straight
// from the MFMA accumulator registers (no v round-trip through LDS):
//   acc[mf][nf][j] = v[row][col], row = mf*16+ldiv*4+j, col = 64w+nf*16+lmod
// 16-lane shfl reduce -> small [8][64][5] LDS buffer -> final 320-thread reduce.
// W is pre-converted to bf16 in d_ws by convW (fallback: in-kernel convert).

#define NN 100000
#define DD 512
#define SS 4
#define BM 64

#define A_BYTES   (BM * DD * 2)              // 65536
#define SAMP_OFF  A_BYTES                    // 65536
#define RED_OFF   (A_BYTES + SS * BM * 4)    // 66560
#define SMEM_SZ   (RED_OFF + 8 * BM * 5 * 4) // 76800

typedef __attribute__((ext_vector_type(8))) short bf16x8;
typedef __attribute__((ext_vector_type(4))) float f32x4;

__device__ __forceinline__ short f2bf(float f) {
  // round-to-nearest-even f32 -> bf16
  unsigned u = __builtin_bit_cast(unsigned, f);
  u += 0x7fffu + ((u >> 16) & 1u);
  return (short)(u >> 16);
}

__global__ __launch_bounds__(256)
void convW(const float* __restrict__ W, short* __restrict__ Wb) {
  int i = (blockIdx.x * 256 + threadIdx.x) * 8;
  f32x4 a = *(const f32x4*)(W + i);
  f32x4 b = *(const f32x4*)(W + i + 4);
  bf16x8 h;
  h[0] = f2bf(a.x); h[1] = f2bf(a.y); h[2] = f2bf(a.z); h[3] = f2bf(a.w);
  h[4] = f2bf(b.x); h[5] = f2bf(b.y); h[6] = f2bf(b.z); h[7] = f2bf(b.w);
  *(bf16x8*)(Wb + i) = h;
}

template <bool PREW>
__global__ __launch_bounds__(512, 4)
void disc2(const float* __restrict__ hc, const float* __restrict__ hpl,
           const int* __restrict__ smp, const float* __restrict__ W,
           const short* __restrict__ Wb, const float* __restrict__ bias,
           float* __restrict__ out) {
  __shared__ __align__(16) char smem[SMEM_SZ];
  int* samp = (int*)(smem + SAMP_OFF);        // [SS][BM]
  float* red = (float*)(smem + RED_OFF);      // [8 waves][BM rows][5]

  const int t = threadIdx.x;
  const int w = t >> 6;        // wave 0..7
  const int l = t & 63;
  const int lmod = l & 15;
  const int ldiv = l >> 4;
  const int n0 = blockIdx.x * BM;

  // ---- stage sample indices ----
  if (t < SS * BM) {
    int s = t >> 6, r = t & 63;
    int n = n0 + r;
    samp[t] = (n < NN) ? smp[s * NN + n] : 0;
  }

  // ---- stage A tile: h_c rows -> bf16 LDS, swizzle byte^=((row&7)<<4) ----
  {
    int row = t >> 3;                 // 8 threads per row
    int c0 = (t & 7) * 64;            // 64 contiguous cols per thread
    int n = n0 + row;
    unsigned rb = (unsigned)row * 1024u;
    unsigned sw = ((unsigned)row & 7u) << 4;
#pragma unroll
    for (int i = 0; i < 8; ++i) {
      int c = c0 + i * 8;
      bf16x8 h;
      if (n < NN) {
        f32x4 x0 = *(const f32x4*)(hc + (size_t)n * DD + c);
        f32x4 x1 = *(const f32x4*)(hc + (size_t)n * DD + c + 4);
        h[0] = f2bf(x0.x); h[1] = f2bf(x0.y); h[2] = f2bf(x0.z); h[3] = f2bf(x0.w);
        h[4] = f2bf(x1.x); h[5] = f2bf(x1.y); h[6] = f2bf(x1.z); h[7] = f2bf(x1.w);
      } else {
        h = (bf16x8)0;                // zero rows beyond N -> v rows = 0
      }
      unsigned addr = rb + (((unsigned)(c * 2)) ^ sw);
      *(bf16x8*)(smem + addr) = h;
    }
  }
  __syncthreads();

  // ---- GEMM: v[0:64][w*64 : w*64+64] via 16x16x32 bf16 MFMA ----
  f32x4 acc[4][4];
#pragma unroll
  for (int i = 0; i < 4; ++i)
#pragma unroll
    for (int j = 0; j < 4; ++j) acc[i][j] = (f32x4)0.0f;

  // B-frag source: Wb[col][k] bf16, col = w*64+nf*16+lmod, k = kt*32+ldiv*8
  const short* wb_base = PREW ? (Wb + (size_t)(w * 64 + lmod) * DD + ldiv * 8) : nullptr;
  const float* wf_base = PREW ? nullptr : (W + (size_t)(w * 64 + lmod) * DD + ldiv * 8);

  for (int kt = 0; kt < DD / 32; ++kt) {
    bf16x8 a[4];
    {
      unsigned ko = (unsigned)(kt * 64 + ldiv * 16);   // byte offset of k within row
#pragma unroll
      for (int mf = 0; mf < 4; ++mf) {
        int row = mf * 16 + lmod;
        unsigned addr = (unsigned)row * 1024u + (ko ^ (((unsigned)row & 7u) << 4));
        a[mf] = *(const bf16x8*)(smem + addr);
      }
    }
#pragma unroll
    for (int nf = 0; nf < 4; ++nf) {
      bf16x8 b;
      if (PREW) {
        b = *(const bf16x8*)(wb_base + nf * 16 * DD + kt * 32);
      } else {
        const float* wp = wf_base + nf * 16 * DD + kt * 32;
        f32x4 w0 = *(const f32x4*)(wp);
        f32x4 w1 = *(const f32x4*)(wp + 4);
        b[0] = f2bf(w0.x); b[1] = f2bf(w0.y); b[2] = f2bf(w0.z); b[3] = f2bf(w0.w);
        b[4] = f2bf(w1.x); b[5] = f2bf(w1.y); b[6] = f2bf(w1.z); b[7] = f2bf(w1.w);
      }
#pragma unroll
      for (int mf = 0; mf < 4; ++mf)
        acc[mf][nf] = __builtin_amdgcn_mfma_f32_16x16x32_bf16(a[mf], b, acc[mf][nf], 0, 0, 0);
    }
  }

  // ---- epilogue: dot v (in regs) against h_pl row + 4 gathered h_c rows ----
  // lane's cols: w*64 + nf*16 + lmod, nf=0..3; rows: mf*16 + ldiv*4 + j
  {
    const int cb = w * 64 + lmod;
#pragma unroll
    for (int mf = 0; mf < 4; ++mf) {
#pragma unroll
      for (int j = 0; j < 4; ++j) {
        int row = mf * 16 + ldiv * 4 + j;
        int n = n0 + row;
        if (n < NN) {
          const float* x0 = hpl + (size_t)n * DD + cb;
          const float* x1 = hc + (size_t)samp[0 * BM + row] * DD + cb;
          const float* x2 = hc + (size_t)samp[1 * BM + row] * DD + cb;
          const float* x3 = hc + (size_t)samp[2 * BM + row] * DD + cb;
          const float* x4 = hc + (size_t)samp[3 * BM + row] * DD + cb;
          float v0 = acc[mf][0][j], v1 = acc[mf][1][j],
                v2 = acc[mf][2][j], v3 = acc[mf][3][j];
          float p0 = x0[0] * v0 + x0[16] * v1 + x0[32] * v2 + x0[48] * v3;
          float p1 = x1[0] * v0 + x1[16] * v1 + x1[32] * v2 + x1[48] * v3;
          float p2 = x2[0] * v0 + x2[16] * v1 + x2[32] * v2 + x2[48] * v3;
          float p3 = x3[0] * v0 + x3[16] * v1 + x3[32] * v2 + x3[48] * v3;
          float p4 = x4[0] * v0 + x4[16] * v1 + x4[32] * v2 + x4[48] * v3;
#pragma unroll
          for (int off = 1; off < 16; off <<= 1) {
            p0 += __shfl_xor(p0, off);
            p1 += __shfl_xor(p1, off);
            p2 += __shfl_xor(p2, off);
            p3 += __shfl_xor(p3, off);
            p4 += __shfl_xor(p4, off);
          }
          if (lmod == 0) {
            float* r = red + ((w << 6) + row) * 5;
            r[0] = p0; r[1] = p1; r[2] = p2; r[3] = p3; r[4] = p4;
          }
        }
      }
    }
  }
  __syncthreads();

  // ---- final reduce over the 8 waves' column-partials + write out ----
  if (t < 5 * BM) {
    int s = t >> 6;          // 0..4
    int row = t & 63;
    int n = n0 + row;
    if (n < NN) {
      float sum = bias[0];
#pragma unroll
      for (int w2 = 0; w2 < 8; ++w2) sum += red[((w2 << 6) + row) * 5 + s];
      if (s == 0) {
        out[n] = sum;                      // sc1
      } else {
        out[s * NN + n] = sum;             // sc2 row s-1
        out[(s + 4) * NN + n] = sum;       // duplicated sc2 row s+3
      }
    }
  }
}

extern "C" void kernel_launch(void* const* d_in, const int* in_sizes, int n_in,
                              void* d_out, int out_size, void* d_ws, size_t ws_size,
                              hipStream_t stream) {
  const float* hc  = (const float*)d_in[0];   // h_c  [1,N,D]
  const float* hpl = (const float*)d_in[1];   // h_pl [1,N,D]
  const int*   smp = (const int*)d_in[2];     // sample_list [S,N]
  const float* W   = (const float*)d_in[3];   // W [1,D,D]
  const float* b   = (const float*)d_in[4];   // b [1]
  float* out = (float*)d_out;                 // [N + 2*S*N]
  (void)in_sizes; (void)n_in; (void)out_size;

  dim3 grid((NN + BM - 1) / BM);   // 1563
  dim3 block(512);

  if (ws_size >= (size_t)(DD * DD * sizeof(short))) {
    short* Wb = (short*)d_ws;
    convW<<<DD * DD / 8 / 256, 256, 0, stream>>>(W, Wb);
    disc2<true><<<grid, block, 0, stream>>>(hc, hpl, smp, W, Wb, b, out);
  } else {
    disc2<false><<<grid, block, 0, stream>>>(hc, hpl, smp, W, nullptr, b, out);
  }
}